// Round 20
// baseline (72.800 us; speedup 1.0000x reference)
//
#include <hip/hip_runtime.h>
#include <math.h>

#define D_MODEL 2048
#define NE      64
#define TB      64               // tokens per gemm tile
#define KHALF   1024             // K per grid-split block (KS=2)
#define KC      64               // fp32 k per chunk
#define NCH     (KHALF / KC)     // 16 chunks
#define FB_KC   32
#define FB_NCH  (D_MODEL / FB_KC)

typedef _Float16 half8 __attribute__((ext_vector_type(8)));
typedef float    f32x4 __attribute__((ext_vector_type(4)));

// two-term split of one float into fp16 high+low at ext-vector slot J.
// Named vars + constant indices only (rule #20 — unions/arrays → scratch).
#define CVT1(F, HV, LV, J) do {                                               \
    float _f = (F);                                                           \
    _Float16 _h = (_Float16)_f;                                               \
    HV[J] = _h;                                                               \
    LV[J] = (_Float16)(_f - (float)_h);                                       \
} while (0)

// ---------------- W -> (Wh, Wl) fp16 split, scaled x64 (r12-proven) ---------
__global__ __launch_bounds__(256) void wcvt_kernel(
    const float* __restrict__ W, short* __restrict__ Wh, short* __restrict__ Wl)
{
    const int e = blockIdx.x, t = threadIdx.x, c = t * 8;
    const float* src = W + (size_t)e * D_MODEL + c;
    float4 v0 = *(const float4*)src;
    float4 v1 = *(const float4*)(src + 4);
    half8 hv, lv;
    CVT1(v0.x * 64.0f, hv, lv, 0); CVT1(v0.y * 64.0f, hv, lv, 1);
    CVT1(v0.z * 64.0f, hv, lv, 2); CVT1(v0.w * 64.0f, hv, lv, 3);
    CVT1(v1.x * 64.0f, hv, lv, 4); CVT1(v1.y * 64.0f, hv, lv, 5);
    CVT1(v1.z * 64.0f, hv, lv, 6); CVT1(v1.w * 64.0f, hv, lv, 7);
    *(half8*)(Wh + (size_t)e * D_MODEL + c) = hv;
    *(half8*)(Wl + (size_t)e * D_MODEL + c) = lv;
}

// ---------------- gemm v4: 32x32 quadrant/wave -> W-read per MFMA halved ----
// 256 thr (4 waves), grid (ntiles, 2). Wave (mp,np) computes tokens
// mp*32..+31 x experts np*32..+31: per kq only 4 W LDS reads (2 n-tiles x
// h/l) feed 16 MFMAs. Per-CU W LDS traffic: r19 4MB -> 1MB. A direct
// global->reg (r18/r19-proven), W dbuf LDS + 1 barrier/chunk (r16/r19).
// Partials scaled 1/512 (exact pow2), summed by r12's proven stats5 ->
// absmax must equal 2.441e-4.
__global__ __launch_bounds__(256, 2) void router_gemm_v4(
    const float* __restrict__ x, const short* __restrict__ Whg,
    const short* __restrict__ Wlg, float* __restrict__ part, int ntiles)
{
    __shared__ __align__(16) char smem[32768];   // 2 bufs x 16KB (Wh 8K + Wl 8K)

    const int t    = threadIdx.x;
    const int tile = blockIdx.x;
    const int ks   = blockIdx.y;
    const int m0   = tile * TB;
    const int k0   = ks * KHALF;
    const int l    = t & 63;
    const int wv   = t >> 6;                 // 0..3
    const int mp   = wv & 1;                 // token-pair half
    const int np   = wv >> 1;                // expert-pair half

    // W staging map (r19-proven, 256 thr): srow 0..63, 2 swizzled slots
    const int srow = t >> 2;
    const int sc   = t & 3;
    const int ssw  = srow & 7;
    const int sof0 = (srow << 6) + (((sc * 2 + 0) ^ ssw) << 3);  // halves
    const int sof1 = (srow << 6) + (((sc * 2 + 1) ^ ssw) << 3);
    const size_t wsrc = (size_t)srow * D_MODEL + k0 + sc * 16;

    // A fragment bases: rows mp*32 + {0,16} + (l&15), k = k0 + ch*64 + kq*32 + (l>>4)*8
    const int koff = (l >> 4) * 8;
    const float* abase0 = x + (size_t)(m0 + mp * 32 +  0 + (l & 15)) * D_MODEL + k0 + koff;
    const float* abase1 = x + (size_t)(m0 + mp * 32 + 16 + (l & 15)) * D_MODEL + k0 + koff;

    f32x4 a00 = {0.f,0.f,0.f,0.f}, a01 = {0.f,0.f,0.f,0.f};  // f0 x n0/n1
    f32x4 a10 = {0.f,0.f,0.f,0.f}, a11 = {0.f,0.f,0.f,0.f};  // f1 x n0/n1

    uint4  whA0, whA1, wlA0, wlA1;           // W stage set even
    uint4  whB0, whB1, wlB0, wlB1;           // W stage set odd
    float4 e00, e01, e02, e03, e10, e11, e12, e13;   // A set even (f0 kq0/1, f1 kq0/1)
    float4 o00, o01, o02, o03, o10, o11, o12, o13;   // A set odd

#define PRE_W(WH0, WH1, WL0, WL1, CH) do {                                    \
    const size_t _o = wsrc + (size_t)(CH) * KC;                               \
    WH0 = *(const uint4*)&Whg[_o];     WH1 = *(const uint4*)&Whg[_o + 8];     \
    WL0 = *(const uint4*)&Wlg[_o];     WL1 = *(const uint4*)&Wlg[_o + 8];     \
} while (0)

#define STORE_W(WH0, WH1, WL0, WL1, BB) do {                                  \
    _Float16* _Wh = (_Float16*)(smem + (BB) * 16384);                         \
    _Float16* _Wl = (_Float16*)(smem + (BB) * 16384 + 8192);                  \
    *(uint4*)&_Wh[sof0] = WH0;  *(uint4*)&_Wh[sof1] = WH1;                    \
    *(uint4*)&_Wl[sof0] = WL0;  *(uint4*)&_Wl[sof1] = WL1;                    \
} while (0)

#define PRE_A(P00, P01, P02, P03, P10, P11, P12, P13, CH) do {                \
    const float* _b0 = abase0 + (size_t)(CH) * KC;                            \
    const float* _b1 = abase1 + (size_t)(CH) * KC;                            \
    P00 = *(const float4*)_b0;        P01 = *(const float4*)(_b0 + 4);        \
    P02 = *(const float4*)(_b0 + 32); P03 = *(const float4*)(_b0 + 36);       \
    P10 = *(const float4*)_b1;        P11 = *(const float4*)(_b1 + 4);        \
    P12 = *(const float4*)(_b1 + 32); P13 = *(const float4*)(_b1 + 36);       \
} while (0)

// one chunk: 2 kq x { 2 A cvt batches + 4 W reads + 16 mfma }
// per-acc 4-term order (al,wl)(al,wh)(ah,wl)(ah,wh), kq ascending (r12 chain)
#define MFMA_PHASE(BB, P00, P01, P02, P03, P10, P11, P12, P13) do {           \
    const _Float16* _Wh = (const _Float16*)(smem + (BB) * 16384);             \
    const _Float16* _Wl = (const _Float16*)(smem + (BB) * 16384 + 8192);      \
    _Pragma("unroll")                                                         \
    for (int kq = 0; kq < 2; ++kq) {                                          \
        half8 ah0, al0, ah1, al1;                                             \
        if (kq == 0) {                                                        \
            CVT1((P00).x * 8.0f, ah0, al0, 0); CVT1((P00).y * 8.0f, ah0, al0, 1); \
            CVT1((P00).z * 8.0f, ah0, al0, 2); CVT1((P00).w * 8.0f, ah0, al0, 3); \
            CVT1((P01).x * 8.0f, ah0, al0, 4); CVT1((P01).y * 8.0f, ah0, al0, 5); \
            CVT1((P01).z * 8.0f, ah0, al0, 6); CVT1((P01).w * 8.0f, ah0, al0, 7); \
            CVT1((P10).x * 8.0f, ah1, al1, 0); CVT1((P10).y * 8.0f, ah1, al1, 1); \
            CVT1((P10).z * 8.0f, ah1, al1, 2); CVT1((P10).w * 8.0f, ah1, al1, 3); \
            CVT1((P11).x * 8.0f, ah1, al1, 4); CVT1((P11).y * 8.0f, ah1, al1, 5); \
            CVT1((P11).z * 8.0f, ah1, al1, 6); CVT1((P11).w * 8.0f, ah1, al1, 7); \
        } else {                                                              \
            CVT1((P02).x * 8.0f, ah0, al0, 0); CVT1((P02).y * 8.0f, ah0, al0, 1); \
            CVT1((P02).z * 8.0f, ah0, al0, 2); CVT1((P02).w * 8.0f, ah0, al0, 3); \
            CVT1((P03).x * 8.0f, ah0, al0, 4); CVT1((P03).y * 8.0f, ah0, al0, 5); \
            CVT1((P03).z * 8.0f, ah0, al0, 6); CVT1((P03).w * 8.0f, ah0, al0, 7); \
            CVT1((P12).x * 8.0f, ah1, al1, 0); CVT1((P12).y * 8.0f, ah1, al1, 1); \
            CVT1((P12).z * 8.0f, ah1, al1, 2); CVT1((P12).w * 8.0f, ah1, al1, 3); \
            CVT1((P13).x * 8.0f, ah1, al1, 4); CVT1((P13).y * 8.0f, ah1, al1, 5); \
            CVT1((P13).z * 8.0f, ah1, al1, 6); CVT1((P13).w * 8.0f, ah1, al1, 7); \
        }                                                                     \
        const int _s = kq * 4 + (l >> 4);                                     \
        _Pragma("unroll")                                                     \
        for (int n = 0; n < 2; ++n) {                                         \
            const int _row  = np * 32 + n * 16 + (l & 15);                    \
            const int _woff = (_row << 6) + (((_s ^ (_row & 7))) << 3);       \
            half8 _wh = *(const half8*)&_Wh[_woff];                           \
            half8 _wl = *(const half8*)&_Wl[_woff];                           \
            f32x4 _a = (n == 0) ? a00 : a01;                                  \
            _a = __builtin_amdgcn_mfma_f32_16x16x32_f16(al0, _wl, _a, 0, 0, 0); \
            _a = __builtin_amdgcn_mfma_f32_16x16x32_f16(al0, _wh, _a, 0, 0, 0); \
            _a = __builtin_amdgcn_mfma_f32_16x16x32_f16(ah0, _wl, _a, 0, 0, 0); \
            _a = __builtin_amdgcn_mfma_f32_16x16x32_f16(ah0, _wh, _a, 0, 0, 0); \
            if (n == 0) a00 = _a; else a01 = _a;                              \
            f32x4 _b = (n == 0) ? a10 : a11;                                  \
            _b = __builtin_amdgcn_mfma_f32_16x16x32_f16(al1, _wl, _b, 0, 0, 0); \
            _b = __builtin_amdgcn_mfma_f32_16x16x32_f16(al1, _wh, _b, 0, 0, 0); \
            _b = __builtin_amdgcn_mfma_f32_16x16x32_f16(ah1, _wl, _b, 0, 0, 0); \
            _b = __builtin_amdgcn_mfma_f32_16x16x32_f16(ah1, _wh, _b, 0, 0, 0); \
            if (n == 0) a10 = _b; else a11 = _b;                              \
        }                                                                     \
    }                                                                         \
} while (0)

    // prologue
    PRE_W(whA0, whA1, wlA0, wlA1, 0);
    STORE_W(whA0, whA1, wlA0, wlA1, 0);
    PRE_W(whB0, whB1, wlB0, wlB1, 1);
    PRE_A(e00, e01, e02, e03, e10, e11, e12, e13, 0);
    PRE_A(o00, o01, o02, o03, o10, o11, o12, o13, 1);
    asm volatile("s_waitcnt lgkmcnt(0)" ::: "memory");
    __builtin_amdgcn_s_barrier();

    for (int ch = 0; ch < NCH; ch += 2) {
        if (ch + 1 < NCH) STORE_W(whB0, whB1, wlB0, wlB1, 1);
        if (ch + 2 < NCH) PRE_W(whA0, whA1, wlA0, wlA1, ch + 2);
        MFMA_PHASE(0, e00, e01, e02, e03, e10, e11, e12, e13);
        if (ch + 2 < NCH) PRE_A(e00, e01, e02, e03, e10, e11, e12, e13, ch + 2);
        asm volatile("s_waitcnt lgkmcnt(0)" ::: "memory");
        __builtin_amdgcn_s_barrier();
        if (ch + 2 < NCH) STORE_W(whA0, whA1, wlA0, wlA1, 0);
        if (ch + 3 < NCH) PRE_W(whB0, whB1, wlB0, wlB1, ch + 3);
        MFMA_PHASE(1, o00, o01, o02, o03, o10, o11, o12, o13);
        if (ch + 3 < NCH) PRE_A(o00, o01, o02, o03, o10, o11, o12, o13, ch + 3);
        asm volatile("s_waitcnt lgkmcnt(0)" ::: "memory");
        __builtin_amdgcn_s_barrier();
    }

    // partials [tile][ks][row 64][e 64], scaled 1/512 (exact pow2; r12-style)
    float* dst = part + ((size_t)tile * 2 + ks) * (TB * NE);
    const int q0 = (l >> 4) * 4;
    const int c0 = np * 32 + (l & 15);
    #pragma unroll
    for (int q = 0; q < 4; ++q) {
        const int r0 = mp * 32 + q0 + q;
        dst[(r0) * NE + c0]           = a00[q] * (1.0f / 512.0f);
        dst[(r0) * NE + c0 + 16]      = a01[q] * (1.0f / 512.0f);
        dst[(r0 + 16) * NE + c0]      = a10[q] * (1.0f / 512.0f);
        dst[(r0 + 16) * NE + c0 + 16] = a11[q] * (1.0f / 512.0f);
    }
}

// ---------------- sum 2 partials + fused stats (r12-proven stats5) ----------
__global__ __launch_bounds__(1024) void router_stats5(
    const float* __restrict__ part, float* __restrict__ out,
    float* __restrict__ ws_prob, float* __restrict__ ws_z,
    int* __restrict__ ws_cnt, int Ntok)
{
    __shared__ float sL[64][NE + 1];
    __shared__ float red16[64][16];
    __shared__ int   arg16[64][16];
    __shared__ float smax[64], sinv[64];
    __shared__ float spart[16][NE];
    __shared__ int   hist[NE];

    const int t = threadIdx.x, b = blockIdx.x, m0 = b * 64;
    const float* base = part + (size_t)b * 2 * (TB * NE);

    {   // sum 2 partials: thread t owns float4 #t (fixed order: deterministic)
        const float* p0 = base + (size_t)t * 4;
        float s0 = 0.f, s1 = 0.f, s2 = 0.f, s3 = 0.f;
        #pragma unroll
        for (int j = 0; j < 2; ++j) {
            float4 v = *(const float4*)(p0 + (size_t)j * (TB * NE));
            s0 += v.x; s1 += v.y; s2 += v.z; s3 += v.w;
        }
        const int row = t >> 4, col = (t & 15) << 2;
        sL[row][col]     = s0; sL[row][col + 1] = s1;
        sL[row][col + 2] = s2; sL[row][col + 3] = s3;
    }
    if (t < NE) hist[t] = 0;
    __syncthreads();

    {   // argmax: 16 threads/token, 4 experts each (ascending -> first-max ok)
        const int m = t >> 4, qr = t & 15;
        float mx = -3.4e38f; int ag = qr * 4;
        #pragma unroll
        for (int k = 0; k < 4; ++k) {
            const int e = qr * 4 + k;
            float v = sL[m][e];
            if (v > mx) { mx = v; ag = e; }
        }
        red16[m][qr] = mx; arg16[m][qr] = ag;
    }
    __syncthreads();
    if (t < 64) {                            // combine ascending: first-max kept
        const int m = t;
        float mx = red16[m][0]; int ag = arg16[m][0];
        #pragma unroll
        for (int qr = 1; qr < 16; ++qr)
            if (red16[m][qr] > mx) { mx = red16[m][qr]; ag = arg16[m][qr]; }
        smax[m] = mx;
        out[m0 + m] = (float)ag;             // expert_index
        atomicAdd(&hist[ag], 1);
    }
    __syncthreads();
    {   // expsum: 16 threads/token
        const int m = t >> 4, qr = t & 15;
        const float mx = smax[m];
        float s = 0.f;
        #pragma unroll
        for (int k = 0; k < 4; ++k) s += expf(sL[m][qr * 4 + k] - mx);
        red16[m][qr] = s;
    }
    __syncthreads();
    if (t < 64) {
        const int m = t;
        float s = 0.f;
        #pragma unroll
        for (int qr = 0; qr < 16; ++qr) s += red16[m][qr];   // fixed order
        float inv = 1.f / s;
        sinv[m] = inv;
        out[Ntok + m0 + m] = inv;            // expert_prob
        float lse = smax[m] + logf(s);
        float z = lse * lse;
        #pragma unroll
        for (int off = 32; off > 0; off >>= 1) z += __shfl_down(z, off, 64);
        if (t == 0) ws_z[b] = z;
    }
    __syncthreads();
    {   // probsum: 16 waves, wave g covers 4 tokens, lane = expert
        const int e = t & 63, g = t >> 6;
        float pa = 0.f;
        #pragma unroll
        for (int k = 0; k < 4; ++k) {
            const int m = g * 4 + k;
            pa += expf(sL[m][e] - smax[m]) * sinv[m];
        }
        spart[g][e] = pa;
    }
    __syncthreads();
    if (t < NE) {
        float ps = 0.f;
        #pragma unroll
        for (int g = 0; g < 16; ++g) ps += spart[g][t];      // fixed order
        ws_prob[b * NE + t] = ps;
        ws_cnt[b * NE + t]  = hist[t];
    }
}

// ---------------- final reduce (r10/r12-proven) -----------------------------
__global__ __launch_bounds__(256) void router_final2(
    const float* __restrict__ ws_prob, const float* __restrict__ ws_z,
    const int* __restrict__ ws_cnt, float* __restrict__ out,
    int Ntok, int nblocks)
{
    __shared__ float sp[4][NE];
    __shared__ int   sc[4][NE];
    __shared__ float sz[4];

    const int e = threadIdx.x & 63, g = threadIdx.x >> 6;
    const int per = nblocks / 4;
    const int hi  = (g == 3) ? nblocks : (g + 1) * per;

    float ps = 0.f; int c = 0;
    for (int blk = g * per; blk < hi; ++blk) {       // fixed partition
        ps += ws_prob[blk * NE + e];
        c  += ws_cnt[blk * NE + e];
    }
    sp[g][e] = ps; sc[g][e] = c;

    float z = 0.f;
    for (int blk = (int)threadIdx.x; blk < nblocks; blk += 256) z += ws_z[blk];
    #pragma unroll
    for (int off = 32; off > 0; off >>= 1) z += __shfl_down(z, off, 64);
    if (e == 0) sz[g] = z;
    __syncthreads();

    if (threadIdx.x < 64) {
        const int ee = threadIdx.x;
        float pst = ((sp[0][ee] + sp[1][ee]) + sp[2][ee]) + sp[3][ee];
        int   ct  = ((sc[0][ee] + sc[1][ee]) + sc[2][ee]) + sc[3][ee];
        out[2 * Ntok + ee] = (float)ct;              // counts

        float fN = (float)Ntok;
        float fp = ((float)ct / fN) * (pst / fN);
        #pragma unroll
        for (int off = 32; off > 0; off >>= 1) fp += __shfl_down(fp, off, 64);
        if (ee == 0) {
            float zt = ((sz[0] + sz[1]) + sz[2]) + sz[3];
            int cap = (Ntok + NE - 1) / NE;
            if (cap < 4) cap = 4;
            float aux = 0.01f * (float)NE * fp + 1e-3f * (zt / fN);
            out[2 * Ntok + NE]     = (float)cap;     // capacity
            out[2 * Ntok + NE + 1] = aux;            // aux_loss
        }
    }
}

// ---------------- fallback (round-1 proven fused fp32 path) -----------------
__global__ __launch_bounds__(256) void router_main_fb(
    const float* __restrict__ x, const float* __restrict__ W,
    float* __restrict__ out, float* __restrict__ ws_prob,
    float* __restrict__ ws_z, int* __restrict__ ws_cnt, int Ntok)
{
    __shared__ __align__(16) float sX[FB_KC][68];
    __shared__ __align__(16) float sW[FB_KC][68];
    __shared__ float sL[64][65];
    __shared__ float smax[64], sinv[64];
    __shared__ float spart[4][NE];
    __shared__ int   hist[NE];

    const int t = threadIdx.x, b = blockIdx.x, m0 = b * 64;
    const int mq = t & 15, nq = t >> 4;
    const int r1 = t >> 3, r2 = r1 + 32, c1 = (t & 7) << 2;
    const float* xp1 = x + (size_t)(m0 + r1) * D_MODEL + c1;
    const float* xp2 = x + (size_t)(m0 + r2) * D_MODEL + c1;
    const float* wp1 = W + (size_t)r1 * D_MODEL + c1;
    const float* wp2 = W + (size_t)r2 * D_MODEL + c1;
    float4 ax1 = *(const float4*)xp1, ax2 = *(const float4*)xp2;
    float4 aw1 = *(const float4*)wp1, aw2 = *(const float4*)wp2;
    float a1[4][4] = {}, a2[4][4] = {};
    for (int ch = 0; ch < FB_NCH; ++ch) {
        __syncthreads();
        sX[c1+0][r1] = ax1.x; sX[c1+1][r1] = ax1.y; sX[c1+2][r1] = ax1.z; sX[c1+3][r1] = ax1.w;
        sX[c1+0][r2] = ax2.x; sX[c1+1][r2] = ax2.y; sX[c1+2][r2] = ax2.z; sX[c1+3][r2] = ax2.w;
        sW[c1+0][r1] = aw1.x; sW[c1+1][r1] = aw1.y; sW[c1+2][r1] = aw1.z; sW[c1+3][r1] = aw1.w;
        sW[c1+0][r2] = aw2.x; sW[c1+1][r2] = aw2.y; sW[c1+2][r2] = aw2.z; sW[c1+3][r2] = aw2.w;
        __syncthreads();
        if (ch + 1 < FB_NCH) {
            xp1 += FB_KC; xp2 += FB_KC; wp1 += FB_KC; wp2 += FB_KC;
            ax1 = *(const float4*)xp1; ax2 = *(const float4*)xp2;
            aw1 = *(const float4*)wp1; aw2 = *(const float4*)wp2;
        }
        #pragma unroll
        for (int k = 0; k < FB_KC; ++k) {
            float4 xa = *(const float4*)&sX[k][mq << 2];
            float4 wb = *(const float4*)&sW[k][nq << 2];
            float (*A)[4] = (k < FB_KC / 2) ? a1 : a2;
            A[0][0] = fmaf(xa.x, wb.x, A[0][0]); A[0][1] = fmaf(xa.x, wb.y, A[0][1]);
            A[0][2] = fmaf(xa.x, wb.z, A[0][2]); A[0][3] = fmaf(xa.x, wb.w, A[0][3]);
            A[1][0] = fmaf(xa.y, wb.x, A[1][0]); A[1][1] = fmaf(xa.y, wb.y, A[1][1]);
            A[1][2] = fmaf(xa.y, wb.z, A[1][2]); A[1][3] = fmaf(xa.y, wb.w, A[1][3]);
            A[2][0] = fmaf(xa.z, wb.x, A[2][0]); A[2][1] = fmaf(xa.z, wb.y, A[2][1]);
            A[2][2] = fmaf(xa.z, wb.z, A[2][2]); A[2][3] = fmaf(xa.z, wb.w, A[2][3]);
            A[3][0] = fmaf(xa.w, wb.x, A[3][0]); A[3][1] = fmaf(xa.w, wb.y, A[3][1]);
            A[3][2] = fmaf(xa.w, wb.z, A[3][2]); A[3][3] = fmaf(xa.w, wb.w, A[3][3]);
        }
    }
    #pragma unroll
    for (int i = 0; i < 4; ++i)
        #pragma unroll
        for (int j = 0; j < 4; ++j)
            sL[(mq << 2) + i][(nq << 2) + j] = a1[i][j] + a2[i][j];
    if (t < NE) hist[t] = 0;
    __syncthreads();
    if (t < 64) {
        const int m = t;
        float mx = sL[m][0]; int arg = 0;
        for (int e = 1; e < NE; ++e) { float v = sL[m][e]; if (v > mx) { mx = v; arg = e; } }
        float s = 0.f;
        for (int e = 0; e < NE; ++e) s += expf(sL[m][e] - mx);
        float inv = 1.f / s;
        out[m0 + m] = (float)arg; out[Ntok + m0 + m] = inv;
        smax[m] = mx; sinv[m] = inv;
        atomicAdd(&hist[arg], 1);
        float lse = mx + logf(s); float z = lse * lse;
        for (int off = 32; off > 0; off >>= 1) z += __shfl_down(z, off, 64);
        if (t == 0) ws_z[b] = z;
    }
    __syncthreads();
    {
        const int e = t & 63, mg = t >> 6;
        float pa = 0.f;
        for (int m = mg * 16; m < mg * 16 + 16; ++m) pa += expf(sL[m][e] - smax[m]) * sinv[m];
        spart[mg][e] = pa;
    }
    __syncthreads();
    if (t < NE) {
        ws_prob[b * NE + t] = spart[0][t] + spart[1][t] + spart[2][t] + spart[3][t];
        ws_cnt[b * NE + t]  = hist[t];
    }
}

extern "C" void kernel_launch(void* const* d_in, const int* in_sizes, int n_in,
                              void* d_out, int out_size, void* d_ws, size_t ws_size,
                              hipStream_t stream)
{
    const float* x = (const float*)d_in[0];
    const float* W = (const float*)d_in[1];
    float* out = (float*)d_out;

    const int Ntok   = in_sizes[0] / D_MODEL;        // 16384
    const int ntiles = Ntok / TB;                    // 256

    const size_t wh_elems   = (size_t)NE * D_MODEL;              // 131072 shorts
    const size_t part_elems = (size_t)ntiles * 2 * TB * NE;      // 2.1M floats
    const size_t need = wh_elems * 2 * 2
                      + (part_elems + (size_t)ntiles * NE + ntiles) * 4
                      + (size_t)ntiles * NE * 4 + 1024;

    if ((Ntok % TB) == 0 && (ntiles % 4) == 0 && ws_size >= need) {
        short* wsh     = (short*)d_ws;               // Wh [64][2048]
        short* wsl     = wsh + wh_elems;             // Wl
        float* ws_part = (float*)(wsl + wh_elems);
        float* ws_prob = ws_part + part_elems;
        float* ws_z    = ws_prob + (size_t)ntiles * NE;
        int*   ws_cnt  = (int*)(ws_z + ntiles);

        wcvt_kernel<<<NE, 256, 0, stream>>>(W, wsh, wsl);
        dim3 grid(ntiles, 2);
        router_gemm_v4<<<grid, 256, 0, stream>>>(x, wsh, wsl, ws_part, ntiles);
        router_stats5<<<ntiles, 1024, 0, stream>>>(ws_part, out, ws_prob, ws_z, ws_cnt, Ntok);
        router_final2<<<1, 256, 0, stream>>>(ws_prob, ws_z, ws_cnt, out, Ntok, ntiles);
    } else {
        const int nb = Ntok / 64;
        float* ws_prob = (float*)d_ws;
        float* ws_z    = ws_prob + (size_t)nb * NE;
        int*   ws_cnt  = (int*)(ws_z + nb);
        router_main_fb<<<nb, 256, 0, stream>>>(x, W, out, ws_prob, ws_z, ws_cnt, Ntok);
        router_final2<<<1, 256, 0, stream>>>(ws_prob, ws_z, ws_cnt, out, Ntok, nb);
    }
}

// Round 21
// 58.453 us; speedup vs baseline: 1.2454x; 1.2454x over previous
//
#include <hip/hip_runtime.h>
#include <math.h>

#define D_MODEL 2048
#define NE      64
#define TB      64               // tokens per fused block
#define KHALF   1024             // K per wave-group (in-block split-K, KS=2)
#define KC      64               // fp32 k per chunk
#define NCH     (KHALF / KC)     // 16 chunks per group
#define FB_KC   32
#define FB_NCH  (D_MODEL / FB_KC)

typedef _Float16 half8 __attribute__((ext_vector_type(8)));
typedef float    f32x4 __attribute__((ext_vector_type(4)));

// two-term split of one float into fp16 high+low at ext-vector slot J.
// Named vars + constant indices only (rule #20 — unions/arrays → scratch).
#define CVT1(F, HV, LV, J) do {                                               \
    float _f = (F);                                                           \
    _Float16 _h = (_Float16)_f;                                               \
    HV[J] = _h;                                                               \
    LV[J] = (_Float16)(_f - (float)_h);                                       \
} while (0)

// ---------------- W -> (Wh, Wl) fp16 split, scaled x64 (r12-proven) ---------
__global__ __launch_bounds__(256) void wcvt_kernel(
    const float* __restrict__ W, short* __restrict__ Wh, short* __restrict__ Wl)
{
    const int e = blockIdx.x, t = threadIdx.x, c = t * 8;
    const float* src = W + (size_t)e * D_MODEL + c;
    float4 v0 = *(const float4*)src;
    float4 v1 = *(const float4*)(src + 4);
    half8 hv, lv;
    CVT1(v0.x * 64.0f, hv, lv, 0); CVT1(v0.y * 64.0f, hv, lv, 1);
    CVT1(v0.z * 64.0f, hv, lv, 2); CVT1(v0.w * 64.0f, hv, lv, 3);
    CVT1(v1.x * 64.0f, hv, lv, 4); CVT1(v1.y * 64.0f, hv, lv, 5);
    CVT1(v1.z * 64.0f, hv, lv, 6); CVT1(v1.w * 64.0f, hv, lv, 7);
    *(half8*)(Wh + (size_t)e * D_MODEL + c) = hv;
    *(half8*)(Wl + (size_t)e * D_MODEL + c) = lv;
}

// ---------------- fused MFMA gemm v3: A direct, W dbuf-LDS, 2 blocks/CU -----
// r19 best-known (58.6us): r16's dbuf W staging + 1 barrier/chunk; r18's A
// path (global->reg, coalesced 4-lanes/line, converted in-reg in the MFMA
// phase). A out of LDS -> 64KB/block -> 2 blocks/CU = 16 waves/CU. W staging
// is a pure byte copy (Wh/Wl preconverted). Math = r14/r16 chain bit-for-bit.
__global__ __launch_bounds__(512, 2) void router_fused_v3(
    const float* __restrict__ x, const short* __restrict__ Whg,
    const short* __restrict__ Wlg, float* __restrict__ out,
    float* __restrict__ ws_prob, float* __restrict__ ws_z,
    int* __restrict__ ws_cnt, int Ntok)
{
    __shared__ __align__(16) char smem[65536];   // 2 groups x 2 bufs x 16KB

    const int t  = threadIdx.x;
    const int b  = blockIdx.x;
    const int m0 = b * TB;
    const int g  = t >> 8;                   // K-half group 0/1
    const int tg = t & 255;
    const int l  = tg & 63;
    const int wv = tg >> 6;                  // token group 0..3
    const int k0 = g * KHALF;

    // group g buf bb -> smem + g*32768 + bb*16384; Wh @0 (8KB), Wl @8KB
    char* gbase = smem + g * 32768;

    // stats region (aliases smem after the loop)
    float (*sL)[NE + 1] = (float (*)[NE + 1])smem;            // 16640 B
    float (*red8)[8]    = (float (*)[8])(smem + 16640);       // 2 KB
    int   (*arg8)[8]    = (int (*)[8])(smem + 18688);         // 2 KB
    float* smax         = (float*)(smem + 20736);
    float* sinv         = (float*)(smem + 20992);
    float (*spart)[NE]  = (float (*)[NE])(smem + 21248);      // 2 KB
    int*   hist         = (int*)(smem + 23296);

    // W staging map: srow = expert row 0..63, sc = slot pair 0..3;
    // slot s (8 halves) stored swizzled at s ^ (srow&7) (r16-proven)
    const int srow = tg >> 2;
    const int sc   = tg & 3;
    const int ssw  = srow & 7;
    const int sof0 = (srow << 6) + (((sc * 2 + 0) ^ ssw) << 3);  // halves
    const int sof1 = (srow << 6) + (((sc * 2 + 1) ^ ssw) << 3);
    const size_t wsrc = (size_t)srow * D_MODEL + k0 + sc * 16;   // halves

    // A fragment base (r18-proven path): token row wv*16+(l&15),
    // k = k0 + ch*64 + kq*32 + (l>>4)*8
    const float* abase = x + (size_t)(m0 + wv * 16 + (l & 15)) * D_MODEL
                           + k0 + ((l >> 4) * 8);

    f32x4 acc0 = {0.f,0.f,0.f,0.f}, acc1 = {0.f,0.f,0.f,0.f};
    f32x4 acc2 = {0.f,0.f,0.f,0.f}, acc3 = {0.f,0.f,0.f,0.f};

    uint4  whA0, whA1, wlA0, wlA1;           // W stage set even
    uint4  whB0, whB1, wlB0, wlB1;           // W stage set odd
    float4 aA0, aA1, aA2, aA3;               // A set even (2 kq x 2 float4)
    float4 aB0, aB1, aB2, aB3;               // A set odd

#define PRE_W(WH0, WH1, WL0, WL1, CH) do {                                    \
    const size_t _o = wsrc + (size_t)(CH) * KC;                               \
    WH0 = *(const uint4*)&Whg[_o];     WH1 = *(const uint4*)&Whg[_o + 8];     \
    WL0 = *(const uint4*)&Wlg[_o];     WL1 = *(const uint4*)&Wlg[_o + 8];     \
} while (0)

#define STORE_W(WH0, WH1, WL0, WL1, BB) do {                                  \
    _Float16* _Wh = (_Float16*)(gbase + (BB) * 16384);                        \
    _Float16* _Wl = (_Float16*)(gbase + (BB) * 16384 + 8192);                 \
    *(uint4*)&_Wh[sof0] = WH0;  *(uint4*)&_Wh[sof1] = WH1;                    \
    *(uint4*)&_Wl[sof0] = WL0;  *(uint4*)&_Wl[sof1] = WL1;                    \
} while (0)

#define PRE_A(PA0, PA1, PA2, PA3, CH) do {                                    \
    const float* _a0 = abase + (size_t)(CH) * KC;                             \
    const float* _a1 = _a0 + 32;                                              \
    PA0 = *(const float4*)_a0; PA1 = *(const float4*)(_a0 + 4);               \
    PA2 = *(const float4*)_a1; PA3 = *(const float4*)(_a1 + 4);               \
} while (0)

// one chunk: 2 kq x { in-reg A cvt (8 CVT1) + 8 W LDS reads + 16 mfma }
// 4-term order (al,wl)(al,wh)(ah,wl)(ah,wh), n ascending — r14/r16 chain
#define MFMA_PHASE(BB, PA0, PA1, PA2, PA3) do {                               \
    const _Float16* _Wh = (const _Float16*)(gbase + (BB) * 16384);            \
    const _Float16* _Wl = (const _Float16*)(gbase + (BB) * 16384 + 8192);     \
    const int _rsw = l & 7;                                                   \
    _Pragma("unroll")                                                         \
    for (int kq = 0; kq < 2; ++kq) {                                          \
        half8 _ah, _al;                                                       \
        if (kq == 0) {                                                        \
            CVT1((PA0).x * 8.0f, _ah, _al, 0); CVT1((PA0).y * 8.0f, _ah, _al, 1); \
            CVT1((PA0).z * 8.0f, _ah, _al, 2); CVT1((PA0).w * 8.0f, _ah, _al, 3); \
            CVT1((PA1).x * 8.0f, _ah, _al, 4); CVT1((PA1).y * 8.0f, _ah, _al, 5); \
            CVT1((PA1).z * 8.0f, _ah, _al, 6); CVT1((PA1).w * 8.0f, _ah, _al, 7); \
        } else {                                                              \
            CVT1((PA2).x * 8.0f, _ah, _al, 0); CVT1((PA2).y * 8.0f, _ah, _al, 1); \
            CVT1((PA2).z * 8.0f, _ah, _al, 2); CVT1((PA2).w * 8.0f, _ah, _al, 3); \
            CVT1((PA3).x * 8.0f, _ah, _al, 4); CVT1((PA3).y * 8.0f, _ah, _al, 5); \
            CVT1((PA3).z * 8.0f, _ah, _al, 6); CVT1((PA3).w * 8.0f, _ah, _al, 7); \
        }                                                                     \
        const int _s = kq * 4 + (l >> 4);                                     \
        _Pragma("unroll")                                                     \
        for (int n = 0; n < 4; ++n) {                                         \
            const int _row  = n * 16 + (l & 15);                              \
            const int _woff = (_row << 6) + (((_s ^ (_row & 7))) << 3);       \
            half8 _wh = *(const half8*)&_Wh[_woff];                           \
            half8 _wl = *(const half8*)&_Wl[_woff];                           \
            f32x4 _a = (n == 0) ? acc0 : (n == 1) ? acc1 : (n == 2) ? acc2 : acc3; \
            _a = __builtin_amdgcn_mfma_f32_16x16x32_f16(_al, _wl, _a, 0, 0, 0); \
            _a = __builtin_amdgcn_mfma_f32_16x16x32_f16(_al, _wh, _a, 0, 0, 0); \
            _a = __builtin_amdgcn_mfma_f32_16x16x32_f16(_ah, _wl, _a, 0, 0, 0); \
            _a = __builtin_amdgcn_mfma_f32_16x16x32_f16(_ah, _wh, _a, 0, 0, 0); \
            if (n == 0) acc0 = _a; else if (n == 1) acc1 = _a;                \
            else if (n == 2) acc2 = _a; else acc3 = _a;                       \
        }                                                                     \
    }                                                                         \
} while (0)

    // prologue
    PRE_W(whA0, whA1, wlA0, wlA1, 0);
    STORE_W(whA0, whA1, wlA0, wlA1, 0);
    PRE_W(whB0, whB1, wlB0, wlB1, 1);
    PRE_A(aA0, aA1, aA2, aA3, 0);
    PRE_A(aB0, aB1, aB2, aB3, 1);
    asm volatile("s_waitcnt lgkmcnt(0)" ::: "memory");
    __builtin_amdgcn_s_barrier();

    for (int ch = 0; ch < NCH; ch += 2) {
        // even chunk: MFMA(buf0, aA) || STORE_W(setB->buf1) || PRE_W(ch+2)
        if (ch + 1 < NCH) STORE_W(whB0, whB1, wlB0, wlB1, 1);
        if (ch + 2 < NCH) PRE_W(whA0, whA1, wlA0, wlA1, ch + 2);
        MFMA_PHASE(0, aA0, aA1, aA2, aA3);
        if (ch + 2 < NCH) PRE_A(aA0, aA1, aA2, aA3, ch + 2);
        asm volatile("s_waitcnt lgkmcnt(0)" ::: "memory");
        __builtin_amdgcn_s_barrier();
        // odd chunk: MFMA(buf1, aB) || STORE_W(setA->buf0) || PRE_W(ch+3)
        if (ch + 2 < NCH) STORE_W(whA0, whA1, wlA0, wlA1, 0);
        if (ch + 3 < NCH) PRE_W(whB0, whB1, wlB0, wlB1, ch + 3);
        MFMA_PHASE(1, aB0, aB1, aB2, aB3);
        if (ch + 3 < NCH) PRE_A(aB0, aB1, aB2, aB3, ch + 3);
        asm volatile("s_waitcnt lgkmcnt(0)" ::: "memory");
        __builtin_amdgcn_s_barrier();
    }

    // ---- combine group accs in LDS (r14-proven, fixed order g0+g1) ----
    __syncthreads();
    const int rbase = wv * 16 + (l >> 4) * 4; // m89 D-layout (proven r11-19)
    const int col0  = l & 15;
    if (g == 1) {
        #pragma unroll
        for (int q = 0; q < 4; ++q) {
            sL[rbase + q][ 0 + col0] = acc0[q];
            sL[rbase + q][16 + col0] = acc1[q];
            sL[rbase + q][32 + col0] = acc2[q];
            sL[rbase + q][48 + col0] = acc3[q];
        }
    }
    __syncthreads();
    if (g == 0) {
        #pragma unroll
        for (int q = 0; q < 4; ++q) {
            sL[rbase + q][ 0 + col0] = (acc0[q] + sL[rbase + q][ 0 + col0]) * (1.0f / 512.0f);
            sL[rbase + q][16 + col0] = (acc1[q] + sL[rbase + q][16 + col0]) * (1.0f / 512.0f);
            sL[rbase + q][32 + col0] = (acc2[q] + sL[rbase + q][32 + col0]) * (1.0f / 512.0f);
            sL[rbase + q][48 + col0] = (acc3[q] + sL[rbase + q][48 + col0]) * (1.0f / 512.0f);
        }
    }
    if (t < NE) hist[t] = 0;
    __syncthreads();

    {   // argmax: 8 threads/token, 8 experts each (ascending -> first-max)
        const int m = t >> 3, qr = t & 7;
        float mx = -3.4e38f; int ag = qr * 8;
        #pragma unroll
        for (int k = 0; k < 8; ++k) {
            const int e = qr * 8 + k;
            float v = sL[m][e];
            if (v > mx) { mx = v; ag = e; }
        }
        red8[m][qr] = mx; arg8[m][qr] = ag;
    }
    __syncthreads();
    if (t < 64) {                             // combine ascending: first-max
        const int m = t;
        float mx = red8[m][0]; int ag = arg8[m][0];
        #pragma unroll
        for (int qr = 1; qr < 8; ++qr)
            if (red8[m][qr] > mx) { mx = red8[m][qr]; ag = arg8[m][qr]; }
        smax[m] = mx;
        out[m0 + m] = (float)ag;              // expert_index
        atomicAdd(&hist[ag], 1);
    }
    __syncthreads();
    {   // expsum: 8 threads/token
        const int m = t >> 3, qr = t & 7;
        const float mx = smax[m];
        float s = 0.f;
        #pragma unroll
        for (int k = 0; k < 8; ++k) s += expf(sL[m][qr * 8 + k] - mx);
        red8[m][qr] = s;
    }
    __syncthreads();
    if (t < 64) {
        const int m = t;
        float s = 0.f;
        #pragma unroll
        for (int qr = 0; qr < 8; ++qr) s += red8[m][qr];     // fixed order
        float inv = 1.f / s;
        sinv[m] = inv;
        out[Ntok + m0 + m] = inv;             // expert_prob
        float lse = smax[m] + logf(s);
        float z = lse * lse;
        #pragma unroll
        for (int off = 32; off > 0; off >>= 1) z += __shfl_down(z, off, 64);
        if (t == 0) ws_z[b] = z;
    }
    __syncthreads();
    {   // probsum: 8 waves, wave gw covers 8 tokens, lane = expert
        const int e = t & 63, gw = t >> 6;
        float pa = 0.f;
        #pragma unroll
        for (int k = 0; k < 8; ++k) {
            const int m = gw * 8 + k;
            pa += expf(sL[m][e] - smax[m]) * sinv[m];
        }
        spart[gw][e] = pa;
    }
    __syncthreads();
    if (t < NE) {
        float ps = 0.f;
        #pragma unroll
        for (int gw = 0; gw < 8; ++gw) ps += spart[gw][t];   // fixed order
        ws_prob[b * NE + t] = ps;
        ws_cnt[b * NE + t]  = hist[t];
    }
}

// ---------------- final reduce (r10/r12-proven) -----------------------------
__global__ __launch_bounds__(256) void router_final2(
    const float* __restrict__ ws_prob, const float* __restrict__ ws_z,
    const int* __restrict__ ws_cnt, float* __restrict__ out,
    int Ntok, int nblocks)
{
    __shared__ float sp[4][NE];
    __shared__ int   sc[4][NE];
    __shared__ float sz[4];

    const int e = threadIdx.x & 63, g = threadIdx.x >> 6;
    const int per = nblocks / 4;
    const int hi  = (g == 3) ? nblocks : (g + 1) * per;

    float ps = 0.f; int c = 0;
    for (int blk = g * per; blk < hi; ++blk) {       // fixed partition
        ps += ws_prob[blk * NE + e];
        c  += ws_cnt[blk * NE + e];
    }
    sp[g][e] = ps; sc[g][e] = c;

    float z = 0.f;
    for (int blk = (int)threadIdx.x; blk < nblocks; blk += 256) z += ws_z[blk];
    #pragma unroll
    for (int off = 32; off > 0; off >>= 1) z += __shfl_down(z, off, 64);
    if (e == 0) sz[g] = z;
    __syncthreads();

    if (threadIdx.x < 64) {
        const int ee = threadIdx.x;
        float pst = ((sp[0][ee] + sp[1][ee]) + sp[2][ee]) + sp[3][ee];
        int   ct  = ((sc[0][ee] + sc[1][ee]) + sc[2][ee]) + sc[3][ee];
        out[2 * Ntok + ee] = (float)ct;              // counts

        float fN = (float)Ntok;
        float fp = ((float)ct / fN) * (pst / fN);
        #pragma unroll
        for (int off = 32; off > 0; off >>= 1) fp += __shfl_down(fp, off, 64);
        if (ee == 0) {
            float zt = ((sz[0] + sz[1]) + sz[2]) + sz[3];
            int cap = (Ntok + NE - 1) / NE;
            if (cap < 4) cap = 4;
            float aux = 0.01f * (float)NE * fp + 1e-3f * (zt / fN);
            out[2 * Ntok + NE]     = (float)cap;     // capacity
            out[2 * Ntok + NE + 1] = aux;            // aux_loss
        }
    }
}

// ---------------- fallback (round-1 proven fused fp32 path) -----------------
__global__ __launch_bounds__(256) void router_main_fb(
    const float* __restrict__ x, const float* __restrict__ W,
    float* __restrict__ out, float* __restrict__ ws_prob,
    float* __restrict__ ws_z, int* __restrict__ ws_cnt, int Ntok)
{
    __shared__ __align__(16) float sX[FB_KC][68];
    __shared__ __align__(16) float sW[FB_KC][68];
    __shared__ float sL[64][65];
    __shared__ float smax[64], sinv[64];
    __shared__ float spart[4][NE];
    __shared__ int   hist[NE];

    const int t = threadIdx.x, b = blockIdx.x, m0 = b * 64;
    const int mq = t & 15, nq = t >> 4;
    const int r1 = t >> 3, r2 = r1 + 32, c1 = (t & 7) << 2;
    const float* xp1 = x + (size_t)(m0 + r1) * D_MODEL + c1;
    const float* xp2 = x + (size_t)(m0 + r2) * D_MODEL + c1;
    const float* wp1 = W + (size_t)r1 * D_MODEL + c1;
    const float* wp2 = W + (size_t)r2 * D_MODEL + c1;
    float4 ax1 = *(const float4*)xp1, ax2 = *(const float4*)xp2;
    float4 aw1 = *(const float4*)wp1, aw2 = *(const float4*)wp2;
    float a1[4][4] = {}, a2[4][4] = {};
    for (int ch = 0; ch < FB_NCH; ++ch) {
        __syncthreads();
        sX[c1+0][r1] = ax1.x; sX[c1+1][r1] = ax1.y; sX[c1+2][r1] = ax1.z; sX[c1+3][r1] = ax1.w;
        sX[c1+0][r2] = ax2.x; sX[c1+1][r2] = ax2.y; sX[c1+2][r2] = ax2.z; sX[c1+3][r2] = ax2.w;
        sW[c1+0][r1] = aw1.x; sW[c1+1][r1] = aw1.y; sW[c1+2][r1] = aw1.z; sW[c1+3][r1] = aw1.w;
        sW[c1+0][r2] = aw2.x; sW[c1+1][r2] = aw2.y; sW[c1+2][r2] = aw2.z; sW[c1+3][r2] = aw2.w;
        __syncthreads();
        if (ch + 1 < FB_NCH) {
            xp1 += FB_KC; xp2 += FB_KC; wp1 += FB_KC; wp2 += FB_KC;
            ax1 = *(const float4*)xp1; ax2 = *(const float4*)xp2;
            aw1 = *(const float4*)wp1; aw2 = *(const float4*)wp2;
        }
        #pragma unroll
        for (int k = 0; k < FB_KC; ++k) {
            float4 xa = *(const float4*)&sX[k][mq << 2];
            float4 wb = *(const float4*)&sW[k][nq << 2];
            float (*A)[4] = (k < FB_KC / 2) ? a1 : a2;
            A[0][0] = fmaf(xa.x, wb.x, A[0][0]); A[0][1] = fmaf(xa.x, wb.y, A[0][1]);
            A[0][2] = fmaf(xa.x, wb.z, A[0][2]); A[0][3] = fmaf(xa.x, wb.w, A[0][3]);
            A[1][0] = fmaf(xa.y, wb.x, A[1][0]); A[1][1] = fmaf(xa.y, wb.y, A[1][1]);
            A[1][2] = fmaf(xa.y, wb.z, A[1][2]); A[1][3] = fmaf(xa.y, wb.w, A[1][3]);
            A[2][0] = fmaf(xa.z, wb.x, A[2][0]); A[2][1] = fmaf(xa.z, wb.y, A[2][1]);
            A[2][2] = fmaf(xa.z, wb.z, A[2][2]); A[2][3] = fmaf(xa.z, wb.w, A[2][3]);
            A[3][0] = fmaf(xa.w, wb.x, A[3][0]); A[3][1] = fmaf(xa.w, wb.y, A[3][1]);
            A[3][2] = fmaf(xa.w, wb.z, A[3][2]); A[3][3] = fmaf(xa.w, wb.w, A[3][3]);
        }
    }
    #pragma unroll
    for (int i = 0; i < 4; ++i)
        #pragma unroll
        for (int j = 0; j < 4; ++j)
            sL[(mq << 2) + i][(nq << 2) + j] = a1[i][j] + a2[i][j];
    if (t < NE) hist[t] = 0;
    __syncthreads();
    if (t < 64) {
        const int m = t;
        float mx = sL[m][0]; int arg = 0;
        for (int e = 1; e < NE; ++e) { float v = sL[m][e]; if (v > mx) { mx = v; arg = e; } }
        float s = 0.f;
        for (int e = 0; e < NE; ++e) s += expf(sL[m][e] - mx);
        float inv = 1.f / s;
        out[m0 + m] = (float)arg; out[Ntok + m0 + m] = inv;
        smax[m] = mx; sinv[m] = inv;
        atomicAdd(&hist[arg], 1);
        float lse = mx + logf(s); float z = lse * lse;
        for (int off = 32; off > 0; off >>= 1) z += __shfl_down(z, off, 64);
        if (t == 0) ws_z[b] = z;
    }
    __syncthreads();
    {
        const int e = t & 63, mg = t >> 6;
        float pa = 0.f;
        for (int m = mg * 16; m < mg * 16 + 16; ++m) pa += expf(sL[m][e] - smax[m]) * sinv[m];
        spart[mg][e] = pa;
    }
    __syncthreads();
    if (t < NE) {
        ws_prob[b * NE + t] = spart[0][t] + spart[1][t] + spart[2][t] + spart[3][t];
        ws_cnt[b * NE + t]  = hist[t];
    }
}

extern "C" void kernel_launch(void* const* d_in, const int* in_sizes, int n_in,
                              void* d_out, int out_size, void* d_ws, size_t ws_size,
                              hipStream_t stream)
{
    const float* x = (const float*)d_in[0];
    const float* W = (const float*)d_in[1];
    float* out = (float*)d_out;

    const int Ntok = in_sizes[0] / D_MODEL;          // 16384
    const int nblk = Ntok / TB;                      // 256

    const size_t wh_elems = (size_t)NE * D_MODEL;    // 131072 shorts each
    const size_t need = wh_elems * 2 * 2
                      + ((size_t)nblk * NE + nblk) * 4
                      + (size_t)nblk * NE * 4 + 1024;

    if ((Ntok % TB) == 0 && (nblk % 4) == 0 && ws_size >= need) {
        short* wsh     = (short*)d_ws;               // Wh [64][2048]
        short* wsl     = wsh + wh_elems;             // Wl
        float* ws_prob = (float*)(wsl + wh_elems);
        float* ws_z    = ws_prob + (size_t)nblk * NE;
        int*   ws_cnt  = (int*)(ws_z + nblk);

        wcvt_kernel<<<NE, 256, 0, stream>>>(W, wsh, wsl);
        router_fused_v3<<<nblk, 512, 0, stream>>>(x, wsh, wsl, out,
                                                  ws_prob, ws_z, ws_cnt, Ntok);
        router_final2<<<1, 256, 0, stream>>>(ws_prob, ws_z, ws_cnt, out, Ntok, nblk);
    } else {
        const int nb = Ntok / 64;
        float* ws_prob = (float*)d_ws;
        float* ws_z    = ws_prob + (size_t)nb * NE;
        int*   ws_cnt  = (int*)(ws_z + nb);
        router_main_fb<<<nb, 256, 0, stream>>>(x, W, out, ws_prob, ws_z, ws_cnt, Ntok);
        router_final2<<<1, 256, 0, stream>>>(ws_prob, ws_z, ws_cnt, out, Ntok, nb);
    }
}